// Round 2
// baseline (126.357 us; speedup 1.0000x reference)
//
#include <hip/hip_runtime.h>

// Problem constants (match reference)
#define B_SZ   2
#define T_CTX  1024
#define E_IN   256
#define D_QK   64
#define DV_OUT 64
#define NROWS  (B_SZ * T_CTX)

// ---------------------------------------------------------------------------
// Kernel 1: per-row projections.
//   q = relu(x@Wq+bq); k = relu(x@Wk+bk); v = x@Wv+bv
//   qpb = q@W1[:64] + b1   (b1 folded in here)
//   kp  = k@W1[64:]
// One block (256 threads) per row; x-row staged in LDS.
// Multi-accumulator unrolling to break the dependent fma chain.
// ---------------------------------------------------------------------------
__global__ __launch_bounds__(256) void proj_kernel(
    const float* __restrict__ x,
    const float* __restrict__ Wq, const float* __restrict__ bq,
    const float* __restrict__ Wk, const float* __restrict__ bk,
    const float* __restrict__ Wv, const float* __restrict__ bv,
    const float* __restrict__ W1, const float* __restrict__ b1,
    float* __restrict__ qpb, float* __restrict__ kp, float* __restrict__ v)
{
    __shared__ float xs[E_IN];
    __shared__ float qs[D_QK];
    __shared__ float ks[D_QK];

    const int row = blockIdx.x;
    const int t   = threadIdx.x;

    xs[t] = x[(size_t)row * E_IN + t];
    __syncthreads();

    const int d   = t & 63;
    const int grp = t >> 6;

    if (grp == 0) {
        float a0 = 0.f, a1 = 0.f, a2 = 0.f, a3 = 0.f;
        #pragma unroll 8
        for (int e = 0; e < E_IN; e += 4) {
            a0 += xs[e]     * Wq[(e)     * D_QK + d];
            a1 += xs[e + 1] * Wq[(e + 1) * D_QK + d];
            a2 += xs[e + 2] * Wq[(e + 2) * D_QK + d];
            a3 += xs[e + 3] * Wq[(e + 3) * D_QK + d];
        }
        qs[d] = fmaxf(bq[d] + ((a0 + a1) + (a2 + a3)), 0.f);
    } else if (grp == 1) {
        float a0 = 0.f, a1 = 0.f, a2 = 0.f, a3 = 0.f;
        #pragma unroll 8
        for (int e = 0; e < E_IN; e += 4) {
            a0 += xs[e]     * Wk[(e)     * D_QK + d];
            a1 += xs[e + 1] * Wk[(e + 1) * D_QK + d];
            a2 += xs[e + 2] * Wk[(e + 2) * D_QK + d];
            a3 += xs[e + 3] * Wk[(e + 3) * D_QK + d];
        }
        ks[d] = fmaxf(bk[d] + ((a0 + a1) + (a2 + a3)), 0.f);
    } else if (grp == 2) {
        float a0 = 0.f, a1 = 0.f, a2 = 0.f, a3 = 0.f;
        #pragma unroll 8
        for (int e = 0; e < E_IN; e += 4) {
            a0 += xs[e]     * Wv[(e)     * DV_OUT + d];
            a1 += xs[e + 1] * Wv[(e + 1) * DV_OUT + d];
            a2 += xs[e + 2] * Wv[(e + 2) * DV_OUT + d];
            a3 += xs[e + 3] * Wv[(e + 3) * DV_OUT + d];
        }
        v[(size_t)row * DV_OUT + d] = bv[d] + ((a0 + a1) + (a2 + a3));
    }
    __syncthreads();

    if (grp == 0) {
        float a0 = 0.f, a1 = 0.f, a2 = 0.f, a3 = 0.f;
        #pragma unroll 4
        for (int e = 0; e < D_QK; e += 4) {
            a0 += qs[e]     * W1[(e)     * D_QK + d];
            a1 += qs[e + 1] * W1[(e + 1) * D_QK + d];
            a2 += qs[e + 2] * W1[(e + 2) * D_QK + d];
            a3 += qs[e + 3] * W1[(e + 3) * D_QK + d];
        }
        qpb[(size_t)row * D_QK + d] = b1[d] + ((a0 + a1) + (a2 + a3));
    } else if (grp == 1) {
        float a0 = 0.f, a1 = 0.f, a2 = 0.f, a3 = 0.f;
        #pragma unroll 4
        for (int e = 0; e < D_QK; e += 4) {
            a0 += ks[e]     * W1[(D_QK + e)     * D_QK + d];
            a1 += ks[e + 1] * W1[(D_QK + e + 1) * D_QK + d];
            a2 += ks[e + 2] * W1[(D_QK + e + 2) * D_QK + d];
            a3 += ks[e + 3] * W1[(D_QK + e + 3) * D_QK + d];
        }
        kp[(size_t)row * D_QK + d] = (a0 + a1) + (a2 + a3);
    }
}

// ---------------------------------------------------------------------------
// Kernel 2: paired-row scored attention.
// Block handles query rows i1=ii and i2=T-1-ii (same batch): combined score
// work is exactly T+1 rows -> perfectly balanced grid, and every kp/v row
// load feeds both queries.
//   s_j = b2 + sum_d relu(qpb[i,d] + kp[j,d]) * W2[d],  j <= i
//   softmax over j, then out = sum_j w_j * v[j,:]
// ---------------------------------------------------------------------------
__global__ __launch_bounds__(256) void attn_kernel(
    const float* __restrict__ qpb, const float* __restrict__ kp,
    const float* __restrict__ v,
    const float* __restrict__ W2, const float* __restrict__ b2,
    float* __restrict__ out)
{
    __shared__ float q1s[D_QK];
    __shared__ float q2s[D_QK];
    __shared__ float w2s[D_QK];
    __shared__ float sc1[T_CTX];
    __shared__ float sc2[T_CTX];
    __shared__ float red[16];
    __shared__ float part1[4][DV_OUT];
    __shared__ float part2[4][DV_OUT];

    const int blk = blockIdx.x;
    const int b   = blk >> 9;            // 512 row-pairs per batch
    const int ii  = blk & 511;
    const int i1  = ii;                  // n1 = ii+1      (<= 512)
    const int i2  = T_CTX - 1 - ii;      // n2 = 1024-ii   (>= 513)
    const int n1  = i1 + 1;
    const int n2  = i2 + 1;              // loop bound (n2 > n1 always)
    const int t    = threadIdx.x;
    const int lane = t & 63;
    const int wave = t >> 6;
    const size_t base = (size_t)b * T_CTX;

    if (t < D_QK) {
        q1s[t] = qpb[(base + i1) * D_QK + t];
        q2s[t] = qpb[(base + i2) * D_QK + t];
        w2s[t] = W2[t];
    }
    __syncthreads();

    const float bias2 = b2[0];
    const float4* q14 = (const float4*)q1s;
    const float4* q24 = (const float4*)q2s;
    const float4* w4  = (const float4*)w2s;

    // ---- scores for both rows, sharing each kp[j] load ----
    float m1l = -INFINITY, m2l = -INFINITY;
    for (int j = t; j < n2; j += 256) {
        const float4* kr = (const float4*)(kp + (base + j) * D_QK);
        float s1x = 0.f, s1y = 0.f, s1z = 0.f, s1w = 0.f;
        float s2x = 0.f, s2y = 0.f, s2z = 0.f, s2w = 0.f;
        #pragma unroll
        for (int dd = 0; dd < D_QK / 4; ++dd) {
            float4 kv = kr[dd];
            float4 q1 = q14[dd];
            float4 q2 = q24[dd];
            float4 wv = w4[dd];
            s1x += fmaxf(q1.x + kv.x, 0.f) * wv.x;
            s1y += fmaxf(q1.y + kv.y, 0.f) * wv.y;
            s1z += fmaxf(q1.z + kv.z, 0.f) * wv.z;
            s1w += fmaxf(q1.w + kv.w, 0.f) * wv.w;
            s2x += fmaxf(q2.x + kv.x, 0.f) * wv.x;
            s2y += fmaxf(q2.y + kv.y, 0.f) * wv.y;
            s2z += fmaxf(q2.z + kv.z, 0.f) * wv.z;
            s2w += fmaxf(q2.w + kv.w, 0.f) * wv.w;
        }
        float s2 = bias2 + ((s2x + s2y) + (s2z + s2w));
        sc2[j] = s2;
        m2l = fmaxf(m2l, s2);
        if (j < n1) {
            float s1 = bias2 + ((s1x + s1y) + (s1z + s1w));
            sc1[j] = s1;
            m1l = fmaxf(m1l, s1);
        }
    }

    // ---- block max (both rows in one pass) ----
    #pragma unroll
    for (int o = 32; o > 0; o >>= 1) {
        m1l = fmaxf(m1l, __shfl_down(m1l, o, 64));
        m2l = fmaxf(m2l, __shfl_down(m2l, o, 64));
    }
    if (lane == 0) { red[wave] = m1l; red[4 + wave] = m2l; }
    __syncthreads();
    const float m1 = fmaxf(fmaxf(red[0], red[1]), fmaxf(red[2], red[3]));
    const float m2 = fmaxf(fmaxf(red[4], red[5]), fmaxf(red[6], red[7]));

    // ---- exp + block sum; zero-pad sc1 in [n1, n2) for branch-free PV ----
    float l1 = 0.f, l2 = 0.f;
    for (int j = t; j < n2; j += 256) {
        float p2 = __expf(sc2[j] - m2);
        sc2[j] = p2;
        l2 += p2;
        float p1 = (j < n1) ? __expf(sc1[j] - m1) : 0.f;
        sc1[j] = p1;
        l1 += p1;
    }
    #pragma unroll
    for (int o = 32; o > 0; o >>= 1) {
        l1 += __shfl_down(l1, o, 64);
        l2 += __shfl_down(l2, o, 64);
    }
    if (lane == 0) { red[8 + wave] = l1; red[12 + wave] = l2; }
    __syncthreads();
    const float denom1 = (red[8] + red[9]) + (red[10] + red[11]);
    const float denom2 = (red[12] + red[13]) + (red[14] + red[15]);

    // ---- PV: lane = dv, waves stride j; each v row feeds both queries ----
    float a1 = 0.f, a2 = 0.f, c1 = 0.f, c2 = 0.f;
    int j = wave * 2;
    for (; j + 1 < n2; j += 8) {
        float vA = v[(base + j)     * DV_OUT + lane];
        float vB = v[(base + j + 1) * DV_OUT + lane];
        a1 += sc1[j] * vA;
        a2 += sc2[j] * vA;
        c1 += sc1[j + 1] * vB;
        c2 += sc2[j + 1] * vB;
    }
    if (j < n2) {
        float vA = v[(base + j) * DV_OUT + lane];
        a1 += sc1[j] * vA;
        a2 += sc2[j] * vA;
    }
    part1[wave][lane] = a1 + c1;
    part2[wave][lane] = a2 + c2;
    __syncthreads();
    if (t < DV_OUT) {
        out[(base + i1) * DV_OUT + t] =
            ((part1[0][t] + part1[1][t]) + (part1[2][t] + part1[3][t])) / denom1;
    } else if (t < 2 * DV_OUT) {
        const int l = t - DV_OUT;
        out[(base + i2) * DV_OUT + l] =
            ((part2[0][l] + part2[1][l]) + (part2[2][l] + part2[3][l])) / denom2;
    }
}

extern "C" void kernel_launch(void* const* d_in, const int* in_sizes, int n_in,
                              void* d_out, int out_size, void* d_ws, size_t ws_size,
                              hipStream_t stream) {
    const float* x  = (const float*)d_in[0];
    const float* Wq = (const float*)d_in[1];
    const float* bq = (const float*)d_in[2];
    const float* Wk = (const float*)d_in[3];
    const float* bk = (const float*)d_in[4];
    const float* Wv = (const float*)d_in[5];
    const float* bv = (const float*)d_in[6];
    const float* W1 = (const float*)d_in[7];
    const float* b1 = (const float*)d_in[8];
    const float* W2 = (const float*)d_in[9];
    const float* b2 = (const float*)d_in[10];
    float* out = (float*)d_out;

    float* ws  = (float*)d_ws;
    float* qpb = ws;                            // NROWS * D_QK
    float* kp  = ws + (size_t)NROWS * D_QK;     // NROWS * D_QK
    float* vv  = ws + (size_t)2 * NROWS * D_QK; // NROWS * DV_OUT

    proj_kernel<<<NROWS, 256, 0, stream>>>(x, Wq, bq, Wk, bk, Wv, bv, W1, b1,
                                           qpb, kp, vv);
    attn_kernel<<<B_SZ * (T_CTX / 2), 256, 0, stream>>>(qpb, kp, vv, W2, b2, out);
}

// Round 3
// 67.238 us; speedup vs baseline: 1.8792x; 1.8792x over previous
//
#include <hip/hip_runtime.h>

// Problem constants (match reference)
#define B_SZ   2
#define T_CTX  1024
#define E_IN   256
#define D_QK   64
#define DV_OUT 64
#define NROWS  (B_SZ * T_CTX)
#define RPB    4   // rows per proj block

// ---------------------------------------------------------------------------
// Kernel 1: projections, 4 rows per block, one row per wave.
//   q = relu(x@Wq+bq); k = relu(x@Wk+bk); v = x@Wv+bv
//   qpb = q@W1[:64] + b1   (row-major [row][d])
//   kpt = (k@W1[64:])^T    (TRANSPOSED: [d][row] -- coalesced score loads)
// Every thread computes the (its-row, its-d) element of q, k AND v, so all
// 4 waves are balanced and each W column is fetched once per block (L1-shared
// across the 4 waves).
// ---------------------------------------------------------------------------
__global__ __launch_bounds__(256) void proj_kernel(
    const float* __restrict__ x,
    const float* __restrict__ Wq, const float* __restrict__ bq,
    const float* __restrict__ Wk, const float* __restrict__ bk,
    const float* __restrict__ Wv, const float* __restrict__ bv,
    const float* __restrict__ W1, const float* __restrict__ b1,
    float* __restrict__ qpb, float* __restrict__ kpt, float* __restrict__ v)
{
    __shared__ float xs[RPB * E_IN];
    __shared__ float qs[RPB * D_QK];
    __shared__ float ks[RPB * D_QK];
    __shared__ float kps[RPB * D_QK];

    const int row0 = blockIdx.x * RPB;
    const int t    = threadIdx.x;

    #pragma unroll
    for (int idx = t; idx < RPB * E_IN; idx += 256)
        xs[idx] = x[(size_t)row0 * E_IN + idx];
    __syncthreads();

    const int d = t & 63;
    const int r = t >> 6;                  // wave -> row
    const float* xrow = &xs[r * E_IN];

    float aq0 = 0.f, aq1 = 0.f, ak0 = 0.f, ak1 = 0.f, av0 = 0.f, av1 = 0.f;
    #pragma unroll 4
    for (int e = 0; e < E_IN; e += 2) {
        float x0 = xrow[e], x1 = xrow[e + 1];
        aq0 += x0 * Wq[(e)     * D_QK   + d];
        aq1 += x1 * Wq[(e + 1) * D_QK   + d];
        ak0 += x0 * Wk[(e)     * D_QK   + d];
        ak1 += x1 * Wk[(e + 1) * D_QK   + d];
        av0 += x0 * Wv[(e)     * DV_OUT + d];
        av1 += x1 * Wv[(e + 1) * DV_OUT + d];
    }
    qs[r * D_QK + d] = fmaxf(aq0 + aq1 + bq[d], 0.f);
    ks[r * D_QK + d] = fmaxf(ak0 + ak1 + bk[d], 0.f);
    v[(size_t)(row0 + r) * DV_OUT + d] = av0 + av1 + bv[d];
    __syncthreads();

    const float* qrow = &qs[r * D_QK];
    const float* krow = &ks[r * D_QK];
    float ap0 = 0.f, ap1 = 0.f, bp0 = 0.f, bp1 = 0.f;
    #pragma unroll 4
    for (int e = 0; e < D_QK; e += 2) {
        float q0 = qrow[e], q1 = qrow[e + 1];
        float k0 = krow[e], k1 = krow[e + 1];
        ap0 += q0 * W1[(e)            * D_QK + d];
        ap1 += q1 * W1[(e + 1)        * D_QK + d];
        bp0 += k0 * W1[(D_QK + e)     * D_QK + d];
        bp1 += k1 * W1[(D_QK + e + 1) * D_QK + d];
    }
    qpb[(size_t)(row0 + r) * D_QK + d] = ap0 + ap1 + b1[d];
    kps[r * D_QK + d] = bp0 + bp1;
    __syncthreads();

    // transposed kp write: 16B per lane instead of 4B-strided scatter
    if (t < D_QK) {
        float4 kq = make_float4(kps[0 * D_QK + t], kps[1 * D_QK + t],
                                kps[2 * D_QK + t], kps[3 * D_QK + t]);
        *(float4*)&kpt[(size_t)t * NROWS + row0] = kq;
    }
}

// ---------------------------------------------------------------------------
// Kernel 2: paired-row scored attention with TRANSPOSED kp.
// Block = (b, pair ii): query rows i1=ii, i2=T-1-ii. Grid = 1024 = exactly
// 4 blocks/CU, zero tail. Thread t owns the j-quad [4t, 4t+3]; the d-loop
// reads kpt[d][base+4t..4t+3] as float4 -> wave reads 1KB CONTIGUOUS per
// instruction. Scores stay in registers through softmax; weights go to LDS
// interleaved (w1,w2 per j) for the PV broadcast pass.
// ---------------------------------------------------------------------------
__global__ __launch_bounds__(256) void attn_kernel(
    const float* __restrict__ qpb, const float* __restrict__ kpt,
    const float* __restrict__ v,
    const float* __restrict__ W2, const float* __restrict__ b2,
    float* __restrict__ out)
{
    __shared__ float q1s[D_QK], q2s[D_QK], w2s[D_QK];
    __shared__ float scp[2 * T_CTX];            // interleaved {w1_j, w2_j}
    __shared__ float red[16];
    __shared__ float part1[4][DV_OUT], part2[4][DV_OUT];

    const int blk = blockIdx.x;
    const int b   = blk >> 9;
    const int ii  = blk & 511;
    const int i1  = ii, i2 = T_CTX - 1 - ii;
    const int n1  = i1 + 1, n2 = i2 + 1;        // n1+n2 = T+1 (balanced)
    const int t    = threadIdx.x;
    const int lane = t & 63;
    const int wave = t >> 6;
    const size_t base = (size_t)b * T_CTX;

    if (t < D_QK) {
        q1s[t] = qpb[(base + i1) * D_QK + t];
        q2s[t] = qpb[(base + i2) * D_QK + t];
        w2s[t] = W2[t];
    }
    __syncthreads();

    const float bias2 = b2[0];
    const int j0 = 4 * t;

    float a10 = 0.f, a11 = 0.f, a12 = 0.f, a13 = 0.f;
    float a20 = 0.f, a21 = 0.f, a22 = 0.f, a23 = 0.f;
    const float* kpb = kpt + base + j0;

#define KP4(dd) (*(const float4*)(kpb + (size_t)(dd) * NROWS))
#define ACC2(kv, q1c, q2c, wc) do {            \
    a10 += fmaxf(q1c + kv.x, 0.f) * wc;        \
    a11 += fmaxf(q1c + kv.y, 0.f) * wc;        \
    a12 += fmaxf(q1c + kv.z, 0.f) * wc;        \
    a13 += fmaxf(q1c + kv.w, 0.f) * wc;        \
    a20 += fmaxf(q2c + kv.x, 0.f) * wc;        \
    a21 += fmaxf(q2c + kv.y, 0.f) * wc;        \
    a22 += fmaxf(q2c + kv.z, 0.f) * wc;        \
    a23 += fmaxf(q2c + kv.w, 0.f) * wc; } while (0)
#define ACCB(kv, q2c, wc) do {                 \
    a20 += fmaxf(q2c + kv.x, 0.f) * wc;        \
    a21 += fmaxf(q2c + kv.y, 0.f) * wc;        \
    a22 += fmaxf(q2c + kv.z, 0.f) * wc;        \
    a23 += fmaxf(q2c + kv.w, 0.f) * wc; } while (0)

    if (j0 < n1) {                              // scores for both queries
        #pragma unroll 2
        for (int dd = 0; dd < D_QK; dd += 4) {
            float4 q1v = *(const float4*)&q1s[dd];
            float4 q2v = *(const float4*)&q2s[dd];
            float4 wv  = *(const float4*)&w2s[dd];
            float4 k0 = KP4(dd), k1 = KP4(dd + 1);
            float4 k2 = KP4(dd + 2), k3 = KP4(dd + 3);
            ACC2(k0, q1v.x, q2v.x, wv.x);
            ACC2(k1, q1v.y, q2v.y, wv.y);
            ACC2(k2, q1v.z, q2v.z, wv.z);
            ACC2(k3, q1v.w, q2v.w, wv.w);
        }
    } else if (j0 < n2) {                       // scores for q2 only
        #pragma unroll 2
        for (int dd = 0; dd < D_QK; dd += 4) {
            float4 q2v = *(const float4*)&q2s[dd];
            float4 wv  = *(const float4*)&w2s[dd];
            float4 k0 = KP4(dd), k1 = KP4(dd + 1);
            float4 k2 = KP4(dd + 2), k3 = KP4(dd + 3);
            ACCB(k0, q2v.x, wv.x);
            ACCB(k1, q2v.y, wv.y);
            ACCB(k2, q2v.z, wv.z);
            ACCB(k3, q2v.w, wv.w);
        }
    }
#undef KP4
#undef ACC2
#undef ACCB

    float s1[4], s2[4];
    s1[0] = (j0 + 0 < n1) ? bias2 + a10 : -INFINITY;
    s1[1] = (j0 + 1 < n1) ? bias2 + a11 : -INFINITY;
    s1[2] = (j0 + 2 < n1) ? bias2 + a12 : -INFINITY;
    s1[3] = (j0 + 3 < n1) ? bias2 + a13 : -INFINITY;
    s2[0] = (j0 + 0 < n2) ? bias2 + a20 : -INFINITY;
    s2[1] = (j0 + 1 < n2) ? bias2 + a21 : -INFINITY;
    s2[2] = (j0 + 2 < n2) ? bias2 + a22 : -INFINITY;
    s2[3] = (j0 + 3 < n2) ? bias2 + a23 : -INFINITY;

    // ---- block max ----
    float m1l = fmaxf(fmaxf(s1[0], s1[1]), fmaxf(s1[2], s1[3]));
    float m2l = fmaxf(fmaxf(s2[0], s2[1]), fmaxf(s2[2], s2[3]));
    #pragma unroll
    for (int o = 32; o > 0; o >>= 1) {
        m1l = fmaxf(m1l, __shfl_xor(m1l, o, 64));
        m2l = fmaxf(m2l, __shfl_xor(m2l, o, 64));
    }
    if (lane == 0) { red[wave] = m1l; red[4 + wave] = m2l; }
    __syncthreads();
    const float m1 = fmaxf(fmaxf(red[0], red[1]), fmaxf(red[2], red[3]));
    const float m2 = fmaxf(fmaxf(red[4], red[5]), fmaxf(red[6], red[7]));

    // ---- exp (registers), interleaved store, block sum ----
    float p1[4], p2[4];
    #pragma unroll
    for (int e = 0; e < 4; ++e) {
        p1[e] = __expf(s1[e] - m1);             // masked -> exp(-inf) = 0
        p2[e] = __expf(s2[e] - m2);
    }
    if (j0 < n2) {
        float4 lo = make_float4(p1[0], p2[0], p1[1], p2[1]);
        float4 hi = make_float4(p1[2], p2[2], p1[3], p2[3]);
        *(float4*)&scp[2 * j0]     = lo;
        *(float4*)&scp[2 * j0 + 4] = hi;
    }
    float l1 = (p1[0] + p1[1]) + (p1[2] + p1[3]);
    float l2 = (p2[0] + p2[1]) + (p2[2] + p2[3]);
    #pragma unroll
    for (int o = 32; o > 0; o >>= 1) {
        l1 += __shfl_xor(l1, o, 64);
        l2 += __shfl_xor(l2, o, 64);
    }
    if (lane == 0) { red[8 + wave] = l1; red[12 + wave] = l2; }
    __syncthreads();
    const float denom1 = (red[8]  + red[9])  + (red[10] + red[11]);
    const float denom2 = (red[12] + red[13]) + (red[14] + red[15]);

    // ---- PV: lane = dv (coalesced v rows), waves stride j, 2x unroll ----
    float x1 = 0.f, x2 = 0.f, y1 = 0.f, y2 = 0.f;
    int j = wave * 2;
    for (; j + 1 < n2; j += 8) {
        float2 wA = *(const float2*)&scp[2 * j];
        float2 wB = *(const float2*)&scp[2 * (j + 1)];
        float vA = v[(base + j)     * DV_OUT + lane];
        float vB = v[(base + j + 1) * DV_OUT + lane];
        x1 += wA.x * vA; x2 += wA.y * vA;
        y1 += wB.x * vB; y2 += wB.y * vB;
    }
    if (j < n2) {
        float2 wA = *(const float2*)&scp[2 * j];
        float vA = v[(base + j) * DV_OUT + lane];
        x1 += wA.x * vA; x2 += wA.y * vA;
    }
    part1[wave][lane] = x1 + y1;
    part2[wave][lane] = x2 + y2;
    __syncthreads();
    if (t < DV_OUT) {
        out[(base + i1) * DV_OUT + t] =
            ((part1[0][t] + part1[1][t]) + (part1[2][t] + part1[3][t])) / denom1;
    } else if (t < 2 * DV_OUT) {
        const int l = t - DV_OUT;
        out[(base + i2) * DV_OUT + l] =
            ((part2[0][l] + part2[1][l]) + (part2[2][l] + part2[3][l])) / denom2;
    }
}

extern "C" void kernel_launch(void* const* d_in, const int* in_sizes, int n_in,
                              void* d_out, int out_size, void* d_ws, size_t ws_size,
                              hipStream_t stream) {
    const float* x  = (const float*)d_in[0];
    const float* Wq = (const float*)d_in[1];
    const float* bq = (const float*)d_in[2];
    const float* Wk = (const float*)d_in[3];
    const float* bk = (const float*)d_in[4];
    const float* Wv = (const float*)d_in[5];
    const float* bv = (const float*)d_in[6];
    const float* W1 = (const float*)d_in[7];
    const float* b1 = (const float*)d_in[8];
    const float* W2 = (const float*)d_in[9];
    const float* b2 = (const float*)d_in[10];
    float* out = (float*)d_out;

    float* ws  = (float*)d_ws;
    float* qpb = ws;                              // NROWS * D_QK   (row-major)
    float* kpt = ws + (size_t)NROWS * D_QK;       // D_QK * NROWS   (TRANSPOSED)
    float* vv  = ws + (size_t)2 * NROWS * D_QK;   // NROWS * DV_OUT (row-major)

    proj_kernel<<<NROWS / RPB, 256, 0, stream>>>(x, Wq, bq, Wk, bk, Wv, bv,
                                                 W1, b1, qpb, kpt, vv);
    attn_kernel<<<B_SZ * (T_CTX / 2), 256, 0, stream>>>(qpb, kpt, vv, W2, b2, out);
}